// Round 10
// baseline (178.869 us; speedup 1.0000x reference)
//
#include <hip/hip_runtime.h>
#include <stdint.h>

#define DN 128
#define AN 128
#define HN 4
#define FN 128
#define L2N 50
#define NPOS (64*200)
#define NEGC (-4294967295.0f)

// ws layout (4B units)
#define OFF_MTWB 0         // u32 [40 tn][4 kk][64 lane][4 jj] : B-frag MT|Wf pairs along dd
#define OFF_GTB  40960     // u32 [8 tn][16 kk][64 lane][4 jj] : B-frag GT pairs along flat hd
#define OFF_CB   73728     // f32 [640] : 0..511 = Wk_h^T bq ; 512..639 = bv@Wf+bf
#define OFF_U    74368     // u32 [12800][256] : u as half2 pairs along outc
#define OFF_R    3351168   // f32 [12800][128] : qe@Wf + B0
#define OFF_PV   4989568   // u32 [12800][256] : pv as half2 pairs, flat hd
#define OFF_EH   8266368   // u32 [100000][64] : E rows as half2 pairs

typedef __fp16 half2v __attribute__((ext_vector_type(2)));
typedef __fp16 f16x8  __attribute__((ext_vector_type(8)));
typedef float  f32x4  __attribute__((ext_vector_type(4)));
union frg { uint4 u; f16x8 h; };

__device__ __forceinline__ uint32_t packh2(float x, float y) {   // RTNE
    union { _Float16 h[2]; uint32_t u; } c; c.h[0] = (_Float16)x; c.h[1] = (_Float16)y;
    return c.u;
}
__device__ __forceinline__ float lo16f(uint32_t u) {
    union { uint32_t u; _Float16 h[2]; } c; c.u = u; return (float)c.h[0];
}
__device__ __forceinline__ float hi16f(uint32_t u) {
    union { uint32_t u; _Float16 h[2]; } c; c.u = u; return (float)c.h[1];
}

// ================= K_PRE_H: fused weight-fold (blocks 0..290) + E->EH cvt (rest) ================
__global__ __launch_bounds__(256) void k_pre_h(
    const float* __restrict__ Wq, const float* __restrict__ bq,
    const float* __restrict__ Wk, const float* __restrict__ bk,
    const float* __restrict__ Wv, const float* __restrict__ bv,
    const float* __restrict__ Wf, const float* __restrict__ bfb,
    const float* __restrict__ E, float* __restrict__ ws)
{
    if (blockIdx.x >= 291) {                 // ---- ecvt part ----
        uint32_t* EH = (uint32_t*)ws + OFF_EH;
        const int tid = (blockIdx.x - 291)*256 + threadIdx.x;
        const int stride = (gridDim.x - 291)*256;
        const int total = 100000*32;         // float4 count
        for (int i = tid; i < total; i += stride) {
            float4 v = ((const float4*)E)[i];
            uint2 p; p.x = packh2(v.x, v.y); p.y = packh2(v.z, v.w);
            ((uint2*)EH)[i] = p;
        }
        return;
    }

    // ---- k0 part ----
    uint32_t* MTWB = (uint32_t*)ws + OFF_MTWB;
    uint32_t* GTBw = (uint32_t*)ws + OFF_GTB;
    float*    CB   = ws + OFF_CB;
    const int idx = blockIdx.x*256 + threadIdx.x;

    if (idx < 40960) {                       // MTWB: pairs along dd
        int jj = idx & 3, lane = (idx>>2)&63, kk = (idx>>8)&3, tn = idx>>10;
        int outc = tn*16 + (lane&15);
        int dd2  = kk*16 + (lane>>4)*4 + jj;
        int dd0  = 2*dd2, dd1 = dd0+1;
        float s0, s1;
        if (outc < 512) {                    // MT[dd][outc] = Wq[dd]_h . Wk[d]_h
            int h = outc >> 7, d = outc & 127;
            const float* wk = Wk + d*AN + h*32;
            const float* q0 = Wq + dd0*AN + h*32;
            const float* q1 = Wq + dd1*AN + h*32;
            s0 = 0.f; s1 = 0.f;
            #pragma unroll 8
            for (int j = 0; j < 32; ++j) { float w = wk[j]; s0 += q0[j]*w; s1 += q1[j]*w; }
        } else {                             // Wf[dd][f]
            int f = outc - 512;
            s0 = Wf[dd0*FN + f]; s1 = Wf[dd1*FN + f];
        }
        MTWB[idx] = packh2(s0, s1);
    } else if (idx < 73728) {                // GTB: pairs along flat hd
        int i2 = idx - 40960;
        int jj = i2 & 3, lane = (i2>>2)&63, kk = (i2>>8)&15, tn = i2>>12;
        int f  = tn*16 + (lane&15);
        int j2 = kk*16 + (lane>>4)*4 + jj;
        int hd0 = 2*j2;
        int h = hd0 >> 7, d0 = hd0 & 127, d1 = d0+1;
        const float* v0 = Wv + d0*AN + h*32;
        const float* v1 = Wv + d1*AN + h*32;
        float s0 = 0.f, s1 = 0.f;
        #pragma unroll 8
        for (int a = 0; a < 32; ++a) {
            float wf = Wf[(h*32+a)*FN + f];
            s0 += v0[a]*wf; s1 += v1[a]*wf;
        }
        GTBw[i2] = packh2(s0, s1);
    } else {                                 // CB
        int c = idx - 73728;
        if (c < 512) {                       // Wk_h^T bq
            int h = c >> 7, d = c & 127;
            float s = 0.f;
            #pragma unroll 8
            for (int j = 0; j < 32; ++j) s += Wk[d*AN + h*32 + j]*bq[h*32 + j];
            CB[c] = s;
        } else if (c < 640) {                // B0 = bv@Wf + bf
            int f = c - 512;
            float s = bfb[f];
            for (int a = 0; a < AN; ++a) s += bv[a]*Wf[a*FN + f];
            CB[c] = s;
        }
    }
}

// ================= K0 (standalone fallback) =================
__global__ __launch_bounds__(256) void k0_pre(
    const float* __restrict__ Wq, const float* __restrict__ bq,
    const float* __restrict__ Wk, const float* __restrict__ bk,
    const float* __restrict__ Wv, const float* __restrict__ bv,
    const float* __restrict__ Wf, const float* __restrict__ bfb,
    float* __restrict__ ws)
{
    uint32_t* MTWB = (uint32_t*)ws + OFF_MTWB;
    uint32_t* GTBw = (uint32_t*)ws + OFF_GTB;
    float*    CB   = ws + OFF_CB;
    const int idx = blockIdx.x*256 + threadIdx.x;

    if (idx < 40960) {
        int jj = idx & 3, lane = (idx>>2)&63, kk = (idx>>8)&3, tn = idx>>10;
        int outc = tn*16 + (lane&15);
        int dd2  = kk*16 + (lane>>4)*4 + jj;
        int dd0  = 2*dd2, dd1 = dd0+1;
        float s0, s1;
        if (outc < 512) {
            int h = outc >> 7, d = outc & 127;
            const float* wk = Wk + d*AN + h*32;
            const float* q0 = Wq + dd0*AN + h*32;
            const float* q1 = Wq + dd1*AN + h*32;
            s0 = 0.f; s1 = 0.f;
            #pragma unroll 8
            for (int j = 0; j < 32; ++j) { float w = wk[j]; s0 += q0[j]*w; s1 += q1[j]*w; }
        } else {
            int f = outc - 512;
            s0 = Wf[dd0*FN + f]; s1 = Wf[dd1*FN + f];
        }
        MTWB[idx] = packh2(s0, s1);
    } else if (idx < 73728) {
        int i2 = idx - 40960;
        int jj = i2 & 3, lane = (i2>>2)&63, kk = (i2>>8)&15, tn = i2>>12;
        int f  = tn*16 + (lane&15);
        int j2 = kk*16 + (lane>>4)*4 + jj;
        int hd0 = 2*j2;
        int h = hd0 >> 7, d0 = hd0 & 127, d1 = d0+1;
        const float* v0 = Wv + d0*AN + h*32;
        const float* v1 = Wv + d1*AN + h*32;
        float s0 = 0.f, s1 = 0.f;
        #pragma unroll 8
        for (int a = 0; a < 32; ++a) {
            float wf = Wf[(h*32+a)*FN + f];
            s0 += v0[a]*wf; s1 += v1[a]*wf;
        }
        GTBw[i2] = packh2(s0, s1);
    } else {
        int c = idx - 73728;
        if (c < 512) {
            int h = c >> 7, d = c & 127;
            float s = 0.f;
            #pragma unroll 8
            for (int j = 0; j < 32; ++j) s += Wk[d*AN + h*32 + j]*bq[h*32 + j];
            CB[c] = s;
        } else if (c < 640) {
            int f = c - 512;
            float s = bfb[f];
            for (int a = 0; a < AN; ++a) s += bv[a]*Wf[a*FN + f];
            CB[c] = s;
        }
    }
}

// ================= K1 v2: MFMA GEMM U|R with block-staged B panel (EH A-side) =================
__global__ __launch_bounds__(256) void k1_proj_h(
    const int* __restrict__ queries, const uint32_t* __restrict__ EH,
    float* __restrict__ ws)
{
    __shared__ __align__(16) uint4 Bp[2048];     // 32 KB panel

    const uint32_t* MTWB = (const uint32_t*)ws + OFF_MTWB;
    const float*    CB   = ws + OFF_CB;
    uint32_t* U = (uint32_t*)ws + OFF_U;
    float*    R = ws + OFF_R;

    const int t = threadIdx.x, wv = t >> 6, ln = t & 63;
    const int g  = blockIdx.x % 5;               // n-group, shared by block
    const int tm = (blockIdx.x / 5)*4 + wv;      // m-tile per wave (0..799)
    const int m = ln & 15, q = ln >> 4;
    const int pos0 = tm*16 + q*4;

    {
        const uint4* src = (const uint4*)(MTWB + (size_t)g*8192);
        #pragma unroll
        for (int j = 0; j < 8; ++j) Bp[t + j*256] = src[t + j*256];
    }

    const int qidx = queries[tm*16 + m];
    const uint4* Eq4 = (const uint4*)(EH + (size_t)qidx*64);
    frg a[4];
    #pragma unroll
    for (int kk = 0; kk < 4; ++kk) a[kk].u = Eq4[kk*4 + q];

    __syncthreads();

    #pragma unroll 1
    for (int i = 0; i < 8; ++i) {
        const int tn = g*8 + i;
        const float cb = CB[tn*16 + m];
        f32x4 c = {cb, cb, cb, cb};
        #pragma unroll
        for (int kk = 0; kk < 4; ++kk) {
            frg b; b.u = Bp[(i*4 + kk)*64 + ln];
            c = __builtin_amdgcn_mfma_f32_16x16x32_f16(a[kk].h, b.h, c, 0, 0, 0);
        }
        if (tn < 32) {
            float p0 = __shfl_xor(c[0], 1);
            float p1 = __shfl_xor(c[1], 1);
            float p2 = __shfl_xor(c[2], 1);
            float p3 = __shfl_xor(c[3], 1);
            if ((ln & 1) == 0) {
                const int ucol = tn*8 + (m >> 1);
                U[(size_t)(pos0+0)*256 + ucol] = packh2(c[0], p0);
                U[(size_t)(pos0+1)*256 + ucol] = packh2(c[1], p1);
                U[(size_t)(pos0+2)*256 + ucol] = packh2(c[2], p2);
                U[(size_t)(pos0+3)*256 + ucol] = packh2(c[3], p3);
            }
        } else {
            const int f = (tn - 32)*16 + m;
            R[(size_t)(pos0+0)*128 + f] = c[0];
            R[(size_t)(pos0+1)*128 + f] = c[1];
            R[(size_t)(pos0+2)*128 + f] = c[2];
            R[(size_t)(pos0+3)*128 + f] = c[3];
        }
    }
}

// ================= K1 (f32 fallback, original) =================
__global__ __launch_bounds__(256) void k1_proj(
    const int* __restrict__ queries, const float* __restrict__ E,
    float* __restrict__ ws)
{
    const uint32_t* MTWB = (const uint32_t*)ws + OFF_MTWB;
    const float*    CB   = ws + OFF_CB;
    uint32_t* U = (uint32_t*)ws + OFF_U;
    float*    R = ws + OFF_R;

    const int t = threadIdx.x, wv = t >> 6, ln = t & 63;
    const int W  = blockIdx.x*4 + wv;
    const int tm = W / 5, g = W - tm*5;
    const int m = ln & 15, q = ln >> 4;
    const int pos0 = tm*16 + q*4;

    const int qidx = queries[tm*16 + m];
    const float* Eq = E + (size_t)qidx * DN;

    frg a[4];
    #pragma unroll
    for (int kk = 0; kk < 4; ++kk) {
        float4 e0 = *(const float4*)(Eq + kk*32 + q*8);
        float4 e1 = *(const float4*)(Eq + kk*32 + q*8 + 4);
        a[kk].u.x = packh2(e0.x, e0.y);
        a[kk].u.y = packh2(e0.z, e0.w);
        a[kk].u.z = packh2(e1.x, e1.y);
        a[kk].u.w = packh2(e1.z, e1.w);
    }

    #pragma unroll 1
    for (int i = 0; i < 8; ++i) {
        const int tn = g*8 + i;
        const float cb = CB[tn*16 + m];
        f32x4 c = {cb, cb, cb, cb};
        #pragma unroll
        for (int kk = 0; kk < 4; ++kk) {
            frg b; b.u = *(const uint4*)(MTWB + ((size_t)(tn*4 + kk)*64 + ln)*4);
            c = __builtin_amdgcn_mfma_f32_16x16x32_f16(a[kk].h, b.h, c, 0, 0, 0);
        }
        if (tn < 32) {
            float p0 = __shfl_xor(c[0], 1);
            float p1 = __shfl_xor(c[1], 1);
            float p2 = __shfl_xor(c[2], 1);
            float p3 = __shfl_xor(c[3], 1);
            if ((ln & 1) == 0) {
                const int ucol = tn*8 + (m >> 1);
                U[(size_t)(pos0+0)*256 + ucol] = packh2(c[0], p0);
                U[(size_t)(pos0+1)*256 + ucol] = packh2(c[1], p1);
                U[(size_t)(pos0+2)*256 + ucol] = packh2(c[2], p2);
                U[(size_t)(pos0+3)*256 + ucol] = packh2(c[3], p3);
            }
        } else {
            const int f = (tn - 32)*16 + m;
            R[(size_t)(pos0+0)*128 + f] = c[0];
            R[(size_t)(pos0+1)*128 + f] = c[1];
            R[(size_t)(pos0+2)*128 + f] = c[2];
            R[(size_t)(pos0+3)*128 + f] = c[3];
        }
    }
}

// ================= K2 v11: grouped-pin pipelined gather (counted waits) =================
// v11 vs v10 (only change is load/wait scheduling; values bit-identical):
//   issue order: f2[0..15] -> bfr (U row) -> f2[16..24]
//   pin {f2[0..15], bfr}   => compiler waits vmcnt(9) (in-order completion)
//   tiles 0-1 pack+MFMA overlap the 9 outstanding tail loads
//   pin f2[16..24]         => vmcnt(0) only before tiles 2-3
__global__ __launch_bounds__(128, 4) void k2_attn_h(
    const int* __restrict__ keys, const uint32_t* __restrict__ EH,
    float* __restrict__ ws)
{
    // per-wave LDS (u32): kT16 [16][68] = 1088 | aT 200 -> 1288; block 2576 (10.3 KB)
    __shared__ __align__(16) uint32_t smem[2576];

    const uint32_t* U  = (const uint32_t*)ws + OFF_U;
    uint32_t*       PV = (uint32_t*)ws + OFF_PV;

    const int t = threadIdx.x, wv = t >> 6, ln = t & 63;
    const int pos = blockIdx.x*2 + wv;
    const int n = ln & 15, qd = ln >> 4;
    const int half = ln >> 5;        // key parity this lane covers
    const int m32 = ln & 31;         // dim-quad: dims 4*m32 .. 4*m32+3

    uint32_t* kT = smem + wv*1288;
    float*    aT = (float*)(smem + wv*1288 + 1088);

    const int* kptr = keys + (size_t)pos*L2N;
    const int myk = kptr[ln < L2N ? ln : 0];

    // ---- issue group A: f2[0..15] ----
    uint2 f2[25];
    #pragma unroll
    for (int i = 0; i < 16; ++i) {
        int row = __shfl(myk, 2*i + half);
        f2[i] = *(const uint2*)(EH + (size_t)row*64 + 2*m32);
    }

    // ---- issue bfr (U row, L2-hot) BETWEEN the gather groups ----
    const uint32_t* Urow = U + (size_t)pos*256;
    frg bfr[4];
    #pragma unroll
    for (int kk = 0; kk < 4; ++kk) {
        if (n < 4) {
            bfr[kk].u = *(const uint4*)(Urow + n*64 + kk*16 + (qd<<2));
        } else if (n == 4) {
            bfr[kk].u.x = 0x3C003C00u; bfr[kk].u.y = 0x3C003C00u;
            bfr[kk].u.z = 0x3C003C00u; bfr[kk].u.w = 0x3C003C00u;
        } else {
            bfr[kk].u.x = 0u; bfr[kk].u.y = 0u; bfr[kk].u.z = 0u; bfr[kk].u.w = 0u;
        }
    }

    // ---- issue group B: f2[16..24] ----
    #pragma unroll
    for (int i = 16; i < 25; ++i) {
        int row = __shfl(myk, 2*i + half);
        f2[i] = *(const uint2*)(EH + (size_t)row*64 + 2*m32);
    }

    // ---- pin group A + bfr: forces their materialization here (wait ~ vmcnt(9)) ----
    #pragma unroll
    for (int i = 0; i < 16; ++i)
        asm volatile("" : "+v"(f2[i].x), "+v"(f2[i].y));
    #pragma unroll
    for (int kk = 0; kk < 4; ++kk)
        asm volatile("" : "+v"(bfr[kk].u.x), "+v"(bfr[kk].u.y),
                          "+v"(bfr[kk].u.z), "+v"(bfr[kk].u.w));

    // ---- tiles 0-1: pack->LDS + MFMA while group B is in flight ----
    f32x4 c[4];
    #pragma unroll
    for (int mt = 0; mt < 2; ++mt) {
        #pragma unroll
        for (int ii = 0; ii < 8; ++ii) {
            const int i = mt*8 + ii;
            const int lk = 2*ii + half;
            *(uint2*)&kT[lk*68 + 2*m32] = f2[i];
        }
        c[mt] = (f32x4){0.f, 0.f, 0.f, 0.f};
        #pragma unroll
        for (int kk = 0; kk < 4; ++kk) {
            frg a; a.u = *(const uint4*)&kT[n*68 + kk*16 + (qd<<2)];
            c[mt] = __builtin_amdgcn_mfma_f32_16x16x32_f16(a.h, bfr[kk].h, c[mt], 0, 0, 0);
        }
    }

    // ---- pin group B (drain) ----
    #pragma unroll
    for (int i = 16; i < 25; ++i)
        asm volatile("" : "+v"(f2[i].x), "+v"(f2[i].y));

    // ---- tiles 2-3 ----
    #pragma unroll
    for (int mt = 2; mt < 4; ++mt) {
        const int icnt = (mt == 3) ? 1 : 8;          // i=24 covers keys 48,49
        #pragma unroll
        for (int ii = 0; ii < 8; ++ii) {
            if (ii < icnt) {
                const int i = mt*8 + ii;
                const int lk = 2*ii + half;
                *(uint2*)&kT[lk*68 + 2*m32] = f2[i];
            }
        }
        c[mt] = (f32x4){0.f, 0.f, 0.f, 0.f};
        #pragma unroll
        for (int kk = 0; kk < 4; ++kk) {
            frg a; a.u = *(const uint4*)&kT[n*68 + kk*16 + (qd<<2)];
            c[mt] = __builtin_amdgcn_mfma_f32_16x16x32_f16(a.h, bfr[kk].h, c[mt], 0, 0, 0);
        }
    }

    // ---- softmax over keys (C-rows) per column (head) ----
    {
        float sc[4][4];
        float mx = -__builtin_inff();
        #pragma unroll
        for (int mt = 0; mt < 4; ++mt) {
            #pragma unroll
            for (int j = 0; j < 4; ++j) {
                float ksv = __shfl(c[mt][j], (ln & 48) | 4);   // ksum lives in col-4 lane
                float v = c[mt][j] * 0.17677669529663687f;
                v = (ksv == 0.0f) ? NEGC : v;
                int key = mt*16 + (qd<<2) + j;
                if (key >= L2N) v = -__builtin_inff();
                sc[mt][j] = v;
                mx = fmaxf(mx, v);
            }
        }
        mx = fmaxf(mx, __shfl_xor(mx, 16));
        mx = fmaxf(mx, __shfl_xor(mx, 32));
        float e[4][4];
        float sum = 0.f;
        #pragma unroll
        for (int mt = 0; mt < 4; ++mt) {
            #pragma unroll
            for (int j = 0; j < 4; ++j) {
                float ev = __expf(sc[mt][j] - mx);
                e[mt][j] = ev; sum += ev;
            }
        }
        sum += __shfl_xor(sum, 16);
        sum += __shfl_xor(sum, 32);
        const float inv = 1.0f / sum;
        if (n < 4) {
            #pragma unroll
            for (int mt = 0; mt < 4; ++mt) {
                #pragma unroll
                for (int j = 0; j < 4; ++j) {
                    int key = mt*16 + (qd<<2) + j;
                    if (key < L2N) aT[key*4 + n] = e[mt][j] * inv;
                }
            }
        }
    }

    // ---- PV from registers: per-parity partials, shfl_xor(32) combine ----
    {
        float p[4][4];
        #pragma unroll
        for (int h = 0; h < 4; ++h)
            #pragma unroll
            for (int d = 0; d < 4; ++d) p[h][d] = 0.f;

        #pragma unroll
        for (int i = 0; i < 25; ++i) {
            const int key = 2*i + half;
            float4 w4 = *(const float4*)&aT[key*4];
            float k0 = lo16f(f2[i].x), k1v = hi16f(f2[i].x);
            float k2v = lo16f(f2[i].y), k3v = hi16f(f2[i].y);
            p[0][0] += w4.x*k0; p[0][1] += w4.x*k1v; p[0][2] += w4.x*k2v; p[0][3] += w4.x*k3v;
            p[1][0] += w4.y*k0; p[1][1] += w4.y*k1v; p[1][2] += w4.y*k2v; p[1][3] += w4.y*k3v;
            p[2][0] += w4.z*k0; p[2][1] += w4.z*k1v; p[2][2] += w4.z*k2v; p[2][3] += w4.z*k3v;
            p[3][0] += w4.w*k0; p[3][1] += w4.w*k1v; p[3][2] += w4.w*k2v; p[3][3] += w4.w*k3v;
        }
        #pragma unroll
        for (int h = 0; h < 4; ++h)
            #pragma unroll
            for (int d = 0; d < 4; ++d)
                p[h][d] += __shfl_xor(p[h][d], 32);

        float a0 = half ? p[2][0] : p[0][0], a1 = half ? p[2][1] : p[0][1];
        float a2 = half ? p[2][2] : p[0][2], a3 = half ? p[2][3] : p[0][3];
        float b0 = half ? p[3][0] : p[1][0], b1 = half ? p[3][1] : p[1][1];
        float b2 = half ? p[3][2] : p[1][2], b3 = half ? p[3][3] : p[1][3];

        uint32_t* PVp = PV + (size_t)pos*256;
        const int hA = 2*half, hB = 2*half + 1;
        *(uint2*)&PVp[hA*64 + 2*m32] = (uint2){ packh2(a0, a1), packh2(a2, a3) };
        *(uint2*)&PVp[hB*64 + 2*m32] = (uint2){ packh2(b0, b1), packh2(b2, b3) };
    }
}

// ================= K2 v7 (fallback when ws too small for EH) =================
__global__ __launch_bounds__(128, 2) void k2_attn(
    const int* __restrict__ keys, const float* __restrict__ E,
    float* __restrict__ ws)
{
    __shared__ __align__(16) uint32_t smem[7748];

    const uint32_t* U  = (const uint32_t*)ws + OFF_U;
    uint32_t*       PV = (uint32_t*)ws + OFF_PV;

    const int t = threadIdx.x, wv = t >> 6, ln = t & 63;
    const int pos = blockIdx.x*2 + wv;
    const int n = ln & 15, qd = ln >> 4;
    const int half = ln >> 5;
    const int m32 = ln & 31;

    uint32_t* kT = smem + wv*3400;
    uint32_t* Us = smem + 6800 + wv*272;
    float*    aT = (float*)(smem + 7344 + wv*200);

    const int* kptr = keys + (size_t)pos*L2N;
    const float* Eg = E + 4*m32;

    const int myk = kptr[ln < L2N ? ln : 0];
    uint4 uv = ((const uint4*)(U + (size_t)pos*256))[ln];

    float4 f4[25];
    #pragma unroll
    for (int i = 0; i < 25; ++i) {
        int row = __shfl(myk, 2*i + half);
        f4[i] = *(const float4*)(Eg + (size_t)row*DN);
    }

    *(uint4*)&Us[qd*68 + (n<<2)] = uv;

    frg bfr[4];
    #pragma unroll
    for (int kk = 0; kk < 4; ++kk) {
        if (n < 4) {
            bfr[kk].u = *(const uint4*)&Us[n*68 + kk*16 + (qd<<2)];
        } else if (n == 4) {
            bfr[kk].u.x = 0x3C003C00u; bfr[kk].u.y = 0x3C003C00u;
            bfr[kk].u.z = 0x3C003C00u; bfr[kk].u.w = 0x3C003C00u;
        } else {
            bfr[kk].u.x = 0u; bfr[kk].u.y = 0u; bfr[kk].u.z = 0u; bfr[kk].u.w = 0u;
        }
    }

    f32x4 c[4];
    #pragma unroll
    for (int mt = 0; mt < 4; ++mt) {
        const int icnt = (mt == 3) ? 1 : 8;
        #pragma unroll
        for (int ii = 0; ii < 8; ++ii) {
            if (ii < icnt) {
                const int i = mt*8 + ii;
                const int key = 2*i + half;
                float4 cur = f4[i];
                uint32_t p0 = packh2(cur.x, cur.y);
                uint32_t p1 = packh2(cur.z, cur.w);
                *(uint2*)&kT[key*68 + 2*m32] = (uint2){p0, p1};
            }
        }
        c[mt] = (f32x4){0.f, 0.f, 0.f, 0.f};
        #pragma unroll
        for (int kk = 0; kk < 4; ++kk) {
            frg a; a.u = *(const uint4*)&kT[(mt*16 + n)*68 + kk*16 + (qd<<2)];
            c[mt] = __builtin_amdgcn_mfma_f32_16x16x32_f16(a.h, bfr[kk].h, c[mt], 0, 0, 0);
        }
    }

    {
        float sc[4][4];
        float mx = -__builtin_inff();
        #pragma unroll
        for (int mt = 0; mt < 4; ++mt) {
            #pragma unroll
            for (int j = 0; j < 4; ++j) {
                float ksv = __shfl(c[mt][j], (ln & 48) | 4);
                float v = c[mt][j] * 0.17677669529663687f;
                v = (ksv == 0.0f) ? NEGC : v;
                int key = mt*16 + (qd<<2) + j;
                if (key >= L2N) v = -__builtin_inff();
                sc[mt][j] = v;
                mx = fmaxf(mx, v);
            }
        }
        mx = fmaxf(mx, __shfl_xor(mx, 16));
        mx = fmaxf(mx, __shfl_xor(mx, 32));
        float e[4][4];
        float sum = 0.f;
        #pragma unroll
        for (int mt = 0; mt < 4; ++mt) {
            #pragma unroll
            for (int j = 0; j < 4; ++j) {
                float ev = __expf(sc[mt][j] - mx);
                e[mt][j] = ev; sum += ev;
            }
        }
        sum += __shfl_xor(sum, 16);
        sum += __shfl_xor(sum, 32);
        const float inv = 1.0f / sum;
        if (n < 4) {
            #pragma unroll
            for (int mt = 0; mt < 4; ++mt) {
                #pragma unroll
                for (int j = 0; j < 4; ++j) {
                    int key = mt*16 + (qd<<2) + j;
                    if (key < L2N) aT[key*4 + n] = e[mt][j] * inv;
                }
            }
        }
    }

    {
        float pa0=0.f,pb0=0.f,pa1=0.f,pb1=0.f,pa2=0.f,pb2=0.f,pa3=0.f,pb3=0.f;
        #pragma unroll
        for (int r = 0; r < L2N; ++r) {
            float4 w4 = *(const float4*)&aT[r*4];
            uint32_t kp = kT[r*68 + ln];
            float kx = lo16f(kp), ky = hi16f(kp);
            pa0 += w4.x*kx; pb0 += w4.x*ky;
            pa1 += w4.y*kx; pb1 += w4.y*ky;
            pa2 += w4.z*kx; pb2 += w4.z*ky;
            pa3 += w4.w*kx; pb3 += w4.w*ky;
        }
        uint32_t* PVp = PV + (size_t)pos*256;
        PVp[0*64 + ln] = packh2(pa0, pb0);
        PVp[1*64 + ln] = packh2(pa1, pb1);
        PVp[2*64 + ln] = packh2(pa2, pb2);
        PVp[3*64 + ln] = packh2(pa3, pb3);
    }
}

// ================= K3 v2: MFMA GEMM out = PV @ GT + R with block-staged B panel =================
__global__ __launch_bounds__(256) void k3_out(
    const float* __restrict__ ws, float* __restrict__ out)
{
    __shared__ __align__(16) uint4 Bp[2048];     // 32 KB panel

    const uint32_t* GTB = (const uint32_t*)ws + OFF_GTB;
    const uint32_t* PV  = (const uint32_t*)ws + OFF_PV;
    const float*    R   = ws + OFF_R;

    const int t = threadIdx.x, wv = t >> 6, ln = t & 63;
    const int g  = blockIdx.x & 3;               // n-group, shared by block
    const int tm = (blockIdx.x >> 2)*4 + wv;     // m-tile per wave (0..799)
    const int m = ln & 15, q = ln >> 4;
    const int pos0 = tm*16 + q*4;

    {
        const uint4* src = (const uint4*)(GTB + (size_t)g*8192);
        #pragma unroll
        for (int j = 0; j < 8; ++j) Bp[t + j*256] = src[t + j*256];
    }

    frg a[16];
    const uint32_t* PVa = PV + (size_t)(tm*16 + m)*256;
    #pragma unroll
    for (int kk = 0; kk < 16; ++kk)
        a[kk].u = *(const uint4*)(PVa + kk*16 + q*4);

    __syncthreads();

    #pragma unroll 1
    for (int i = 0; i < 2; ++i) {
        const int nt = g*2 + i;
        const int f = nt*16 + m;
        f32x4 c;
        c[0] = R[(size_t)(pos0+0)*128 + f];
        c[1] = R[(size_t)(pos0+1)*128 + f];
        c[2] = R[(size_t)(pos0+2)*128 + f];
        c[3] = R[(size_t)(pos0+3)*128 + f];
        #pragma unroll
        for (int kk = 0; kk < 16; ++kk) {
            frg b; b.u = Bp[(i*16 + kk)*64 + ln];
            c = __builtin_amdgcn_mfma_f32_16x16x32_f16(a[kk].h, b.h, c, 0, 0, 0);
        }
        out[(size_t)(pos0+0)*128 + f] = c[0];
        out[(size_t)(pos0+1)*128 + f] = c[1];
        out[(size_t)(pos0+2)*128 + f] = c[2];
        out[(size_t)(pos0+3)*128 + f] = c[3];
    }
}

extern "C" void kernel_launch(void* const* d_in, const int* in_sizes, int n_in,
                              void* d_out, int out_size, void* d_ws, size_t ws_size,
                              hipStream_t stream) {
    const int* queries = (const int*)d_in[0];
    const int* keys    = (const int*)d_in[1];
    const float* E   = (const float*)d_in[2];
    const float* Wq  = (const float*)d_in[3];
    const float* bq  = (const float*)d_in[4];
    const float* Wk  = (const float*)d_in[5];
    const float* bk  = (const float*)d_in[6];
    const float* Wv  = (const float*)d_in[7];
    const float* bv  = (const float*)d_in[8];
    const float* Wf  = (const float*)d_in[9];
    const float* bfb = (const float*)d_in[10];
    float* ws = (float*)d_ws;
    float* o  = (float*)d_out;

    const size_t need = ((size_t)OFF_EH + 100000ull*64ull) * 4ull;
    const bool useEH = (ws_size >= need);

    if (useEH) {
        hipLaunchKernelGGL(k_pre_h, dim3(291 + 2048), dim3(256), 0, stream,
                           Wq, bq, Wk, bk, Wv, bv, Wf, bfb, E, ws);
        hipLaunchKernelGGL(k1_proj_h, dim3(1000), dim3(256), 0, stream,
                           queries, (const uint32_t*)ws + OFF_EH, ws);
        hipLaunchKernelGGL(k2_attn_h, dim3(6400), dim3(128), 0, stream,
                           keys, (const uint32_t*)ws + OFF_EH, ws);
    } else {
        hipLaunchKernelGGL(k0_pre,  dim3(291),  dim3(256), 0, stream,
                           Wq, bq, Wk, bk, Wv, bv, Wf, bfb, ws);
        hipLaunchKernelGGL(k1_proj, dim3(1000), dim3(256), 0, stream, queries, E, ws);
        hipLaunchKernelGGL(k2_attn, dim3(6400), dim3(128), 0, stream, keys, E, ws);
    }
    hipLaunchKernelGGL(k3_out,  dim3(800),  dim3(256), 0, stream, ws, o);
}

// Round 11
// 163.356 us; speedup vs baseline: 1.0950x; 1.0950x over previous
//
#include <hip/hip_runtime.h>
#include <stdint.h>

#define DN 128
#define AN 128
#define HN 4
#define FN 128
#define L2N 50
#define NPOS (64*200)
#define NEGC (-4294967295.0f)

// ws layout (4B units)
#define OFF_MTWB 0         // u32 [40 tn][4 kk][64 lane][4 jj] : B-frag MT|Wf pairs along dd
#define OFF_GTB  40960     // u32 [8 tn][16 kk][64 lane][4 jj] : B-frag GT pairs along flat hd
#define OFF_CB   73728     // f32 [640] : 0..511 = Wk_h^T bq ; 512..639 = bv@Wf+bf
#define OFF_U    74368     // u32 [12800][256] : u as half2 pairs along outc
#define OFF_R    3351168   // f32 [12800][128] : qe@Wf + B0
#define OFF_PV   4989568   // u32 [12800][256] : pv as half2 pairs, flat hd
#define OFF_EH   8266368   // u32 [100000][64] : E rows as half2 pairs

typedef __fp16 half2v __attribute__((ext_vector_type(2)));
typedef __fp16 f16x8  __attribute__((ext_vector_type(8)));
typedef float  f32x4  __attribute__((ext_vector_type(4)));
union frg { uint4 u; f16x8 h; };

__device__ __forceinline__ uint32_t packh2(float x, float y) {   // RTNE
    union { _Float16 h[2]; uint32_t u; } c; c.h[0] = (_Float16)x; c.h[1] = (_Float16)y;
    return c.u;
}
__device__ __forceinline__ float lo16f(uint32_t u) {
    union { uint32_t u; _Float16 h[2]; } c; c.u = u; return (float)c.h[0];
}
__device__ __forceinline__ float hi16f(uint32_t u) {
    union { uint32_t u; _Float16 h[2]; } c; c.u = u; return (float)c.h[1];
}

// ================= K_PRE_H: fused weight-fold (blocks 0..290) + E->EH cvt (rest) ================
// The two halves are fully independent (k0: W* -> MTWB/GTB/CB; ecvt: E -> EH).
// Fusing lets the latency-bound weight-fold co-schedule under the BW-bound E stream.
__global__ __launch_bounds__(256) void k_pre_h(
    const float* __restrict__ Wq, const float* __restrict__ bq,
    const float* __restrict__ Wk, const float* __restrict__ bk,
    const float* __restrict__ Wv, const float* __restrict__ bv,
    const float* __restrict__ Wf, const float* __restrict__ bfb,
    const float* __restrict__ E, float* __restrict__ ws)
{
    if (blockIdx.x >= 291) {                 // ---- ecvt part ----
        uint32_t* EH = (uint32_t*)ws + OFF_EH;
        const int tid = (blockIdx.x - 291)*256 + threadIdx.x;
        const int stride = (gridDim.x - 291)*256;
        const int total = 100000*32;         // float4 count
        for (int i = tid; i < total; i += stride) {
            float4 v = ((const float4*)E)[i];
            uint2 p; p.x = packh2(v.x, v.y); p.y = packh2(v.z, v.w);
            ((uint2*)EH)[i] = p;
        }
        return;
    }

    // ---- k0 part ----
    uint32_t* MTWB = (uint32_t*)ws + OFF_MTWB;
    uint32_t* GTBw = (uint32_t*)ws + OFF_GTB;
    float*    CB   = ws + OFF_CB;
    const int idx = blockIdx.x*256 + threadIdx.x;

    if (idx < 40960) {                       // MTWB: pairs along dd
        int jj = idx & 3, lane = (idx>>2)&63, kk = (idx>>8)&3, tn = idx>>10;
        int outc = tn*16 + (lane&15);
        int dd2  = kk*16 + (lane>>4)*4 + jj;
        int dd0  = 2*dd2, dd1 = dd0+1;
        float s0, s1;
        if (outc < 512) {                    // MT[dd][outc] = Wq[dd]_h . Wk[d]_h
            int h = outc >> 7, d = outc & 127;
            const float* wk = Wk + d*AN + h*32;
            const float* q0 = Wq + dd0*AN + h*32;
            const float* q1 = Wq + dd1*AN + h*32;
            s0 = 0.f; s1 = 0.f;
            #pragma unroll 8
            for (int j = 0; j < 32; ++j) { float w = wk[j]; s0 += q0[j]*w; s1 += q1[j]*w; }
        } else {                             // Wf[dd][f]
            int f = outc - 512;
            s0 = Wf[dd0*FN + f]; s1 = Wf[dd1*FN + f];
        }
        MTWB[idx] = packh2(s0, s1);
    } else if (idx < 73728) {                // GTB: pairs along flat hd
        int i2 = idx - 40960;
        int jj = i2 & 3, lane = (i2>>2)&63, kk = (i2>>8)&15, tn = i2>>12;
        int f  = tn*16 + (lane&15);
        int j2 = kk*16 + (lane>>4)*4 + jj;
        int hd0 = 2*j2;
        int h = hd0 >> 7, d0 = hd0 & 127, d1 = d0+1;
        const float* v0 = Wv + d0*AN + h*32;
        const float* v1 = Wv + d1*AN + h*32;
        float s0 = 0.f, s1 = 0.f;
        #pragma unroll 8
        for (int a = 0; a < 32; ++a) {
            float wf = Wf[(h*32+a)*FN + f];
            s0 += v0[a]*wf; s1 += v1[a]*wf;
        }
        GTBw[i2] = packh2(s0, s1);
    } else {                                 // CB
        int c = idx - 73728;
        if (c < 512) {                       // Wk_h^T bq
            int h = c >> 7, d = c & 127;
            float s = 0.f;
            #pragma unroll 8
            for (int j = 0; j < 32; ++j) s += Wk[d*AN + h*32 + j]*bq[h*32 + j];
            CB[c] = s;
        } else if (c < 640) {                // B0 = bv@Wf + bf
            int f = c - 512;
            float s = bfb[f];
            for (int a = 0; a < AN; ++a) s += bv[a]*Wf[a*FN + f];
            CB[c] = s;
        }
    }
}

// ================= K0 (standalone fallback) =================
__global__ __launch_bounds__(256) void k0_pre(
    const float* __restrict__ Wq, const float* __restrict__ bq,
    const float* __restrict__ Wk, const float* __restrict__ bk,
    const float* __restrict__ Wv, const float* __restrict__ bv,
    const float* __restrict__ Wf, const float* __restrict__ bfb,
    float* __restrict__ ws)
{
    uint32_t* MTWB = (uint32_t*)ws + OFF_MTWB;
    uint32_t* GTBw = (uint32_t*)ws + OFF_GTB;
    float*    CB   = ws + OFF_CB;
    const int idx = blockIdx.x*256 + threadIdx.x;

    if (idx < 40960) {
        int jj = idx & 3, lane = (idx>>2)&63, kk = (idx>>8)&3, tn = idx>>10;
        int outc = tn*16 + (lane&15);
        int dd2  = kk*16 + (lane>>4)*4 + jj;
        int dd0  = 2*dd2, dd1 = dd0+1;
        float s0, s1;
        if (outc < 512) {
            int h = outc >> 7, d = outc & 127;
            const float* wk = Wk + d*AN + h*32;
            const float* q0 = Wq + dd0*AN + h*32;
            const float* q1 = Wq + dd1*AN + h*32;
            s0 = 0.f; s1 = 0.f;
            #pragma unroll 8
            for (int j = 0; j < 32; ++j) { float w = wk[j]; s0 += q0[j]*w; s1 += q1[j]*w; }
        } else {
            int f = outc - 512;
            s0 = Wf[dd0*FN + f]; s1 = Wf[dd1*FN + f];
        }
        MTWB[idx] = packh2(s0, s1);
    } else if (idx < 73728) {
        int i2 = idx - 40960;
        int jj = i2 & 3, lane = (i2>>2)&63, kk = (i2>>8)&15, tn = i2>>12;
        int f  = tn*16 + (lane&15);
        int j2 = kk*16 + (lane>>4)*4 + jj;
        int hd0 = 2*j2;
        int h = hd0 >> 7, d0 = hd0 & 127, d1 = d0+1;
        const float* v0 = Wv + d0*AN + h*32;
        const float* v1 = Wv + d1*AN + h*32;
        float s0 = 0.f, s1 = 0.f;
        #pragma unroll 8
        for (int a = 0; a < 32; ++a) {
            float wf = Wf[(h*32+a)*FN + f];
            s0 += v0[a]*wf; s1 += v1[a]*wf;
        }
        GTBw[i2] = packh2(s0, s1);
    } else {
        int c = idx - 73728;
        if (c < 512) {
            int h = c >> 7, d = c & 127;
            float s = 0.f;
            #pragma unroll 8
            for (int j = 0; j < 32; ++j) s += Wk[d*AN + h*32 + j]*bq[h*32 + j];
            CB[c] = s;
        } else if (c < 640) {
            int f = c - 512;
            float s = bfb[f];
            for (int a = 0; a < AN; ++a) s += bv[a]*Wf[a*FN + f];
            CB[c] = s;
        }
    }
}

// ================= K1 v2: MFMA GEMM U|R with block-staged B panel (EH A-side) =================
__global__ __launch_bounds__(256) void k1_proj_h(
    const int* __restrict__ queries, const uint32_t* __restrict__ EH,
    float* __restrict__ ws)
{
    __shared__ __align__(16) uint4 Bp[2048];     // 32 KB panel

    const uint32_t* MTWB = (const uint32_t*)ws + OFF_MTWB;
    const float*    CB   = ws + OFF_CB;
    uint32_t* U = (uint32_t*)ws + OFF_U;
    float*    R = ws + OFF_R;

    const int t = threadIdx.x, wv = t >> 6, ln = t & 63;
    const int g  = blockIdx.x % 5;               // n-group, shared by block
    const int tm = (blockIdx.x / 5)*4 + wv;      // m-tile per wave (0..799)
    const int m = ln & 15, q = ln >> 4;
    const int pos0 = tm*16 + q*4;

    {
        const uint4* src = (const uint4*)(MTWB + (size_t)g*8192);
        #pragma unroll
        for (int j = 0; j < 8; ++j) Bp[t + j*256] = src[t + j*256];
    }

    const int qidx = queries[tm*16 + m];
    const uint4* Eq4 = (const uint4*)(EH + (size_t)qidx*64);
    frg a[4];
    #pragma unroll
    for (int kk = 0; kk < 4; ++kk) a[kk].u = Eq4[kk*4 + q];

    __syncthreads();

    #pragma unroll 1
    for (int i = 0; i < 8; ++i) {
        const int tn = g*8 + i;
        const float cb = CB[tn*16 + m];
        f32x4 c = {cb, cb, cb, cb};
        #pragma unroll
        for (int kk = 0; kk < 4; ++kk) {
            frg b; b.u = Bp[(i*4 + kk)*64 + ln];
            c = __builtin_amdgcn_mfma_f32_16x16x32_f16(a[kk].h, b.h, c, 0, 0, 0);
        }
        if (tn < 32) {
            float p0 = __shfl_xor(c[0], 1);
            float p1 = __shfl_xor(c[1], 1);
            float p2 = __shfl_xor(c[2], 1);
            float p3 = __shfl_xor(c[3], 1);
            if ((ln & 1) == 0) {
                const int ucol = tn*8 + (m >> 1);
                U[(size_t)(pos0+0)*256 + ucol] = packh2(c[0], p0);
                U[(size_t)(pos0+1)*256 + ucol] = packh2(c[1], p1);
                U[(size_t)(pos0+2)*256 + ucol] = packh2(c[2], p2);
                U[(size_t)(pos0+3)*256 + ucol] = packh2(c[3], p3);
            }
        } else {
            const int f = (tn - 32)*16 + m;
            R[(size_t)(pos0+0)*128 + f] = c[0];
            R[(size_t)(pos0+1)*128 + f] = c[1];
            R[(size_t)(pos0+2)*128 + f] = c[2];
            R[(size_t)(pos0+3)*128 + f] = c[3];
        }
    }
}

// ================= K1 (f32 fallback, original) =================
__global__ __launch_bounds__(256) void k1_proj(
    const int* __restrict__ queries, const float* __restrict__ E,
    float* __restrict__ ws)
{
    const uint32_t* MTWB = (const uint32_t*)ws + OFF_MTWB;
    const float*    CB   = ws + OFF_CB;
    uint32_t* U = (uint32_t*)ws + OFF_U;
    float*    R = ws + OFF_R;

    const int t = threadIdx.x, wv = t >> 6, ln = t & 63;
    const int W  = blockIdx.x*4 + wv;
    const int tm = W / 5, g = W - tm*5;
    const int m = ln & 15, q = ln >> 4;
    const int pos0 = tm*16 + q*4;

    const int qidx = queries[tm*16 + m];
    const float* Eq = E + (size_t)qidx * DN;

    frg a[4];
    #pragma unroll
    for (int kk = 0; kk < 4; ++kk) {
        float4 e0 = *(const float4*)(Eq + kk*32 + q*8);
        float4 e1 = *(const float4*)(Eq + kk*32 + q*8 + 4);
        a[kk].u.x = packh2(e0.x, e0.y);
        a[kk].u.y = packh2(e0.z, e0.w);
        a[kk].u.z = packh2(e1.x, e1.y);
        a[kk].u.w = packh2(e1.z, e1.w);
    }

    #pragma unroll 1
    for (int i = 0; i < 8; ++i) {
        const int tn = g*8 + i;
        const float cb = CB[tn*16 + m];
        f32x4 c = {cb, cb, cb, cb};
        #pragma unroll
        for (int kk = 0; kk < 4; ++kk) {
            frg b; b.u = *(const uint4*)(MTWB + ((size_t)(tn*4 + kk)*64 + ln)*4);
            c = __builtin_amdgcn_mfma_f32_16x16x32_f16(a[kk].h, b.h, c, 0, 0, 0);
        }
        if (tn < 32) {
            float p0 = __shfl_xor(c[0], 1);
            float p1 = __shfl_xor(c[1], 1);
            float p2 = __shfl_xor(c[2], 1);
            float p3 = __shfl_xor(c[3], 1);
            if ((ln & 1) == 0) {
                const int ucol = tn*8 + (m >> 1);
                U[(size_t)(pos0+0)*256 + ucol] = packh2(c[0], p0);
                U[(size_t)(pos0+1)*256 + ucol] = packh2(c[1], p1);
                U[(size_t)(pos0+2)*256 + ucol] = packh2(c[2], p2);
                U[(size_t)(pos0+3)*256 + ucol] = packh2(c[3], p3);
            }
        } else {
            const int f = (tn - 32)*16 + m;
            R[(size_t)(pos0+0)*128 + f] = c[0];
            R[(size_t)(pos0+1)*128 + f] = c[1];
            R[(size_t)(pos0+2)*128 + f] = c[2];
            R[(size_t)(pos0+3)*128 + f] = c[3];
        }
    }
}

// ================= K2 v10: f16-E gather, pinned window, direct-global B-frags =================
// v10 vs v8: Us LDS staging deleted — bfr[kk] loads directly from the position's
// U row in global (algebra: Us[n*68+kk*16+4qd] == U[pos*256 + n*64 + kk*16 + 4qd]).
__global__ __launch_bounds__(128, 4) void k2_attn_h(
    const int* __restrict__ keys, const uint32_t* __restrict__ EH,
    float* __restrict__ ws)
{
    // per-wave LDS (u32): kT16 [16][68] = 1088 | aT 200 -> 1288; block 2576 (10.3 KB)
    __shared__ __align__(16) uint32_t smem[2576];

    const uint32_t* U  = (const uint32_t*)ws + OFF_U;
    uint32_t*       PV = (uint32_t*)ws + OFF_PV;

    const int t = threadIdx.x, wv = t >> 6, ln = t & 63;
    const int pos = blockIdx.x*2 + wv;
    const int n = ln & 15, qd = ln >> 4;
    const int half = ln >> 5;        // key parity this lane covers
    const int m32 = ln & 31;         // dim-quad: dims 4*m32 .. 4*m32+3

    uint32_t* kT = smem + wv*1288;
    float*    aT = (float*)(smem + wv*1288 + 1088);

    const int* kptr = keys + (size_t)pos*L2N;

    const int myk = kptr[ln < L2N ? ln : 0];

    // ---- gather: ALL 25 uint2 loads (2 keys/instr) ----
    uint2 f2[25];
    #pragma unroll
    for (int i = 0; i < 25; ++i) {
        int row = __shfl(myk, 2*i + half);
        f2[i] = *(const uint2*)(EH + (size_t)row*64 + 2*m32);
    }
    #pragma unroll
    for (int i = 0; i < 25; ++i)
        asm volatile("" : "+v"(f2[i].x), "+v"(f2[i].y));

    // ---- B-fragments direct from global U row (L2-hot) ----
    const uint32_t* Urow = U + (size_t)pos*256;
    frg bfr[4];
    #pragma unroll
    for (int kk = 0; kk < 4; ++kk) {
        if (n < 4) {
            bfr[kk].u = *(const uint4*)(Urow + n*64 + kk*16 + (qd<<2));
        } else if (n == 4) {
            bfr[kk].u.x = 0x3C003C00u; bfr[kk].u.y = 0x3C003C00u;
            bfr[kk].u.z = 0x3C003C00u; bfr[kk].u.w = 0x3C003C00u;
        } else {
            bfr[kk].u.x = 0u; bfr[kk].u.y = 0u; bfr[kk].u.z = 0u; bfr[kk].u.w = 0u;
        }
    }

    // ---- QK^T per 16-key tile through the rotating LDS buffer ----
    f32x4 c[4];
    #pragma unroll
    for (int mt = 0; mt < 4; ++mt) {
        const int icnt = (mt == 3) ? 1 : 8;
        #pragma unroll
        for (int ii = 0; ii < 8; ++ii) {
            if (ii < icnt) {
                const int i = mt*8 + ii;
                const int lk = 2*ii + half;
                *(uint2*)&kT[lk*68 + 2*m32] = f2[i];
            }
        }
        c[mt] = (f32x4){0.f, 0.f, 0.f, 0.f};
        #pragma unroll
        for (int kk = 0; kk < 4; ++kk) {
            frg a; a.u = *(const uint4*)&kT[n*68 + kk*16 + (qd<<2)];
            c[mt] = __builtin_amdgcn_mfma_f32_16x16x32_f16(a.h, bfr[kk].h, c[mt], 0, 0, 0);
        }
    }

    // ---- softmax over keys (C-rows) per column (head) ----
    {
        float sc[4][4];
        float mx = -__builtin_inff();
        #pragma unroll
        for (int mt = 0; mt < 4; ++mt) {
            #pragma unroll
            for (int j = 0; j < 4; ++j) {
                float ksv = __shfl(c[mt][j], (ln & 48) | 4);
                float v = c[mt][j] * 0.17677669529663687f;
                v = (ksv == 0.0f) ? NEGC : v;
                int key = mt*16 + (qd<<2) + j;
                if (key >= L2N) v = -__builtin_inff();
                sc[mt][j] = v;
                mx = fmaxf(mx, v);
            }
        }
        mx = fmaxf(mx, __shfl_xor(mx, 16));
        mx = fmaxf(mx, __shfl_xor(mx, 32));
        float e[4][4];
        float sum = 0.f;
        #pragma unroll
        for (int mt = 0; mt < 4; ++mt) {
            #pragma unroll
            for (int j = 0; j < 4; ++j) {
                float ev = __expf(sc[mt][j] - mx);
                e[mt][j] = ev; sum += ev;
            }
        }
        sum += __shfl_xor(sum, 16);
        sum += __shfl_xor(sum, 32);
        const float inv = 1.0f / sum;
        if (n < 4) {
            #pragma unroll
            for (int mt = 0; mt < 4; ++mt) {
                #pragma unroll
                for (int j = 0; j < 4; ++j) {
                    int key = mt*16 + (qd<<2) + j;
                    if (key < L2N) aT[key*4 + n] = e[mt][j] * inv;
                }
            }
        }
    }

    // ---- PV from registers: per-parity partials, shfl_xor(32) combine ----
    {
        float p[4][4];
        #pragma unroll
        for (int h = 0; h < 4; ++h)
            #pragma unroll
            for (int d = 0; d < 4; ++d) p[h][d] = 0.f;

        #pragma unroll
        for (int i = 0; i < 25; ++i) {
            const int key = 2*i + half;
            float4 w4 = *(const float4*)&aT[key*4];
            float k0 = lo16f(f2[i].x), k1v = hi16f(f2[i].x);
            float k2v = lo16f(f2[i].y), k3v = hi16f(f2[i].y);
            p[0][0] += w4.x*k0; p[0][1] += w4.x*k1v; p[0][2] += w4.x*k2v; p[0][3] += w4.x*k3v;
            p[1][0] += w4.y*k0; p[1][1] += w4.y*k1v; p[1][2] += w4.y*k2v; p[1][3] += w4.y*k3v;
            p[2][0] += w4.z*k0; p[2][1] += w4.z*k1v; p[2][2] += w4.z*k2v; p[2][3] += w4.z*k3v;
            p[3][0] += w4.w*k0; p[3][1] += w4.w*k1v; p[3][2] += w4.w*k2v; p[3][3] += w4.w*k3v;
        }
        #pragma unroll
        for (int h = 0; h < 4; ++h)
            #pragma unroll
            for (int d = 0; d < 4; ++d)
                p[h][d] += __shfl_xor(p[h][d], 32);

        float a0 = half ? p[2][0] : p[0][0], a1 = half ? p[2][1] : p[0][1];
        float a2 = half ? p[2][2] : p[0][2], a3 = half ? p[2][3] : p[0][3];
        float b0 = half ? p[3][0] : p[1][0], b1 = half ? p[3][1] : p[1][1];
        float b2 = half ? p[3][2] : p[1][2], b3 = half ? p[3][3] : p[1][3];

        uint32_t* PVp = PV + (size_t)pos*256;
        const int hA = 2*half, hB = 2*half + 1;
        *(uint2*)&PVp[hA*64 + 2*m32] = (uint2){ packh2(a0, a1), packh2(a2, a3) };
        *(uint2*)&PVp[hB*64 + 2*m32] = (uint2){ packh2(b0, b1), packh2(b2, b3) };
    }
}

// ================= K2 v7 (fallback when ws too small for EH) =================
__global__ __launch_bounds__(128, 2) void k2_attn(
    const int* __restrict__ keys, const float* __restrict__ E,
    float* __restrict__ ws)
{
    __shared__ __align__(16) uint32_t smem[7748];

    const uint32_t* U  = (const uint32_t*)ws + OFF_U;
    uint32_t*       PV = (uint32_t*)ws + OFF_PV;

    const int t = threadIdx.x, wv = t >> 6, ln = t & 63;
    const int pos = blockIdx.x*2 + wv;
    const int n = ln & 15, qd = ln >> 4;
    const int half = ln >> 5;
    const int m32 = ln & 31;

    uint32_t* kT = smem + wv*3400;
    uint32_t* Us = smem + 6800 + wv*272;
    float*    aT = (float*)(smem + 7344 + wv*200);

    const int* kptr = keys + (size_t)pos*L2N;
    const float* Eg = E + 4*m32;

    const int myk = kptr[ln < L2N ? ln : 0];
    uint4 uv = ((const uint4*)(U + (size_t)pos*256))[ln];

    float4 f4[25];
    #pragma unroll
    for (int i = 0; i < 25; ++i) {
        int row = __shfl(myk, 2*i + half);
        f4[i] = *(const float4*)(Eg + (size_t)row*DN);
    }

    *(uint4*)&Us[qd*68 + (n<<2)] = uv;

    frg bfr[4];
    #pragma unroll
    for (int kk = 0; kk < 4; ++kk) {
        if (n < 4) {
            bfr[kk].u = *(const uint4*)&Us[n*68 + kk*16 + (qd<<2)];
        } else if (n == 4) {
            bfr[kk].u.x = 0x3C003C00u; bfr[kk].u.y = 0x3C003C00u;
            bfr[kk].u.z = 0x3C003C00u; bfr[kk].u.w = 0x3C003C00u;
        } else {
            bfr[kk].u.x = 0u; bfr[kk].u.y = 0u; bfr[kk].u.z = 0u; bfr[kk].u.w = 0u;
        }
    }

    f32x4 c[4];
    #pragma unroll
    for (int mt = 0; mt < 4; ++mt) {
        const int icnt = (mt == 3) ? 1 : 8;
        #pragma unroll
        for (int ii = 0; ii < 8; ++ii) {
            if (ii < icnt) {
                const int i = mt*8 + ii;
                const int key = 2*i + half;
                float4 cur = f4[i];
                uint32_t p0 = packh2(cur.x, cur.y);
                uint32_t p1 = packh2(cur.z, cur.w);
                *(uint2*)&kT[key*68 + 2*m32] = (uint2){p0, p1};
            }
        }
        c[mt] = (f32x4){0.f, 0.f, 0.f, 0.f};
        #pragma unroll
        for (int kk = 0; kk < 4; ++kk) {
            frg a; a.u = *(const uint4*)&kT[(mt*16 + n)*68 + kk*16 + (qd<<2)];
            c[mt] = __builtin_amdgcn_mfma_f32_16x16x32_f16(a.h, bfr[kk].h, c[mt], 0, 0, 0);
        }
    }

    {
        float sc[4][4];
        float mx = -__builtin_inff();
        #pragma unroll
        for (int mt = 0; mt < 4; ++mt) {
            #pragma unroll
            for (int j = 0; j < 4; ++j) {
                float ksv = __shfl(c[mt][j], (ln & 48) | 4);
                float v = c[mt][j] * 0.17677669529663687f;
                v = (ksv == 0.0f) ? NEGC : v;
                int key = mt*16 + (qd<<2) + j;
                if (key >= L2N) v = -__builtin_inff();
                sc[mt][j] = v;
                mx = fmaxf(mx, v);
            }
        }
        mx = fmaxf(mx, __shfl_xor(mx, 16));
        mx = fmaxf(mx, __shfl_xor(mx, 32));
        float e[4][4];
        float sum = 0.f;
        #pragma unroll
        for (int mt = 0; mt < 4; ++mt) {
            #pragma unroll
            for (int j = 0; j < 4; ++j) {
                float ev = __expf(sc[mt][j] - mx);
                e[mt][j] = ev; sum += ev;
            }
        }
        sum += __shfl_xor(sum, 16);
        sum += __shfl_xor(sum, 32);
        const float inv = 1.0f / sum;
        if (n < 4) {
            #pragma unroll
            for (int mt = 0; mt < 4; ++mt) {
                #pragma unroll
                for (int j = 0; j < 4; ++j) {
                    int key = mt*16 + (qd<<2) + j;
                    if (key < L2N) aT[key*4 + n] = e[mt][j] * inv;
                }
            }
        }
    }

    {
        float pa0=0.f,pb0=0.f,pa1=0.f,pb1=0.f,pa2=0.f,pb2=0.f,pa3=0.f,pb3=0.f;
        #pragma unroll
        for (int r = 0; r < L2N; ++r) {
            float4 w4 = *(const float4*)&aT[r*4];
            uint32_t kp = kT[r*68 + ln];
            float kx = lo16f(kp), ky = hi16f(kp);
            pa0 += w4.x*kx; pb0 += w4.x*ky;
            pa1 += w4.y*kx; pb1 += w4.y*ky;
            pa2 += w4.z*kx; pb2 += w4.z*ky;
            pa3 += w4.w*kx; pb3 += w4.w*ky;
        }
        uint32_t* PVp = PV + (size_t)pos*256;
        PVp[0*64 + ln] = packh2(pa0, pb0);
        PVp[1*64 + ln] = packh2(pa1, pb1);
        PVp[2*64 + ln] = packh2(pa2, pb2);
        PVp[3*64 + ln] = packh2(pa3, pb3);
    }
}

// ================= K3 v2: MFMA GEMM out = PV @ GT + R with block-staged B panel =================
__global__ __launch_bounds__(256) void k3_out(
    const float* __restrict__ ws, float* __restrict__ out)
{
    __shared__ __align__(16) uint4 Bp[2048];     // 32 KB panel

    const uint32_t* GTB = (const uint32_t*)ws + OFF_GTB;
    const uint32_t* PV  = (const uint32_t*)ws + OFF_PV;
    const float*    R   = ws + OFF_R;

    const int t = threadIdx.x, wv = t >> 6, ln = t & 63;
    const int g  = blockIdx.x & 3;               // n-group, shared by block
    const int tm = (blockIdx.x >> 2)*4 + wv;     // m-tile per wave (0..799)
    const int m = ln & 15, q = ln >> 4;
    const int pos0 = tm*16 + q*4;

    {
        const uint4* src = (const uint4*)(GTB + (size_t)g*8192);
        #pragma unroll
        for (int j = 0; j < 8; ++j) Bp[t + j*256] = src[t + j*256];
    }

    frg a[16];
    const uint32_t* PVa = PV + (size_t)(tm*16 + m)*256;
    #pragma unroll
    for (int kk = 0; kk < 16; ++kk)
        a[kk].u = *(const uint4*)(PVa + kk*16 + q*4);

    __syncthreads();

    #pragma unroll 1
    for (int i = 0; i < 2; ++i) {
        const int nt = g*2 + i;
        const int f = nt*16 + m;
        f32x4 c;
        c[0] = R[(size_t)(pos0+0)*128 + f];
        c[1] = R[(size_t)(pos0+1)*128 + f];
        c[2] = R[(size_t)(pos0+2)*128 + f];
        c[3] = R[(size_t)(pos0+3)*128 + f];
        #pragma unroll
        for (int kk = 0; kk < 16; ++kk) {
            frg b; b.u = Bp[(i*16 + kk)*64 + ln];
            c = __builtin_amdgcn_mfma_f32_16x16x32_f16(a[kk].h, b.h, c, 0, 0, 0);
        }
        out[(size_t)(pos0+0)*128 + f] = c[0];
        out[(size_t)(pos0+1)*128 + f] = c[1];
        out[(size_t)(pos0+2)*128 + f] = c[2];
        out[(size_t)(pos0+3)*128 + f] = c[3];
    }
}

extern "C" void kernel_launch(void* const* d_in, const int* in_sizes, int n_in,
                              void* d_out, int out_size, void* d_ws, size_t ws_size,
                              hipStream_t stream) {
    const int* queries = (const int*)d_in[0];
    const int* keys    = (const int*)d_in[1];
    const float* E   = (const float*)d_in[2];
    const float* Wq  = (const float*)d_in[3];
    const float* bq  = (const float*)d_in[4];
    const float* Wk  = (const float*)d_in[5];
    const float* bk  = (const float*)d_in[6];
    const float* Wv  = (const float*)d_in[7];
    const float* bv  = (const float*)d_in[8];
    const float* Wf  = (const float*)d_in[9];
    const float* bfb = (const float*)d_in[10];
    float* ws = (float*)d_ws;
    float* o  = (float*)d_out;

    const size_t need = ((size_t)OFF_EH + 100000ull*64ull) * 4ull;
    const bool useEH = (ws_size >= need);

    if (useEH) {
        hipLaunchKernelGGL(k_pre_h, dim3(291 + 2048), dim3(256), 0, stream,
                           Wq, bq, Wk, bk, Wv, bv, Wf, bfb, E, ws);
        hipLaunchKernelGGL(k1_proj_h, dim3(1000), dim3(256), 0, stream,
                           queries, (const uint32_t*)ws + OFF_EH, ws);
        hipLaunchKernelGGL(k2_attn_h, dim3(6400), dim3(128), 0, stream,
                           keys, (const uint32_t*)ws + OFF_EH, ws);
    } else {
        hipLaunchKernelGGL(k0_pre,  dim3(291),  dim3(256), 0, stream,
                           Wq, bq, Wk, bk, Wv, bv, Wf, bfb, ws);
        hipLaunchKernelGGL(k1_proj, dim3(1000), dim3(256), 0, stream, queries, E, ws);
        hipLaunchKernelGGL(k2_attn, dim3(6400), dim3(128), 0, stream, keys, E, ws);
    }
    hipLaunchKernelGGL(k3_out,  dim3(800),  dim3(256), 0, stream, ws, o);
}